// Round 5
// baseline (92.502 us; speedup 1.0000x reference)
//
#include <hip/hip_runtime.h>

#define N_MSG 8192
#define DIM 256
#define KS 5
#define THRESH 0.2f
#define FILT 0.196f                          // bf16-filter margin (~16 sigma)
#define N_TEMPORAL (2*(N_MSG-1))             // 16382
#define N_EDGES (N_TEMPORAL + N_MSG*KS)      // 57342
#define ATTR_OFF (2*N_EDGES)                 // 114684
#define VALID_OFF (ATTR_OFF + N_EDGES*64)    // 3784572
#define BM 128
#define NTILE (N_MSG / BM)                   // 64
#define NBLOCKS (NTILE*(NTILE+1)/2)          // 2080
#define CAP 32

typedef __bf16 bf16x8 __attribute__((ext_vector_type(8)));
typedef __bf16 bf16x4 __attribute__((ext_vector_type(4)));
typedef float  f32x4  __attribute__((ext_vector_type(4)));

__device__ __forceinline__ void gload_lds16(const void* g, void* l) {
    __builtin_amdgcn_global_load_lds(
        (const __attribute__((address_space(1))) void*)g,
        (__attribute__((address_space(3))) void*)l, 16, 0, 0);
}

// Insert (v, j) into descending-sorted top-5 (ties: lower index first).
__device__ __forceinline__ void ins5(float v, int j, float (&vv)[KS], int (&xx)[KS]) {
    float cv = v; int cj = j;
#pragma unroll
    for (int k = 0; k < KS; ++k) {
        bool b = (cv > vv[k]) || (cv == vv[k] && cj < xx[k]);
        float tv = b ? vv[k] : cv; int tj = b ? xx[k] : cj;
        vv[k] = b ? cv : vv[k];    xx[k] = b ? cj : xx[k];
        cv = tv; cj = tj;
    }
}

// ---- Kernel A: L2-normalize rows (fp32 + bf16 copy), zero counters -------
__global__ void normalize_k(const float* __restrict__ emb, float* __restrict__ embn,
                            __bf16* __restrict__ embh, int* __restrict__ cnt) {
    int lane = threadIdx.x & 63;
    int row = blockIdx.x * 4 + (threadIdx.x >> 6);
    const float4 x = *(const float4*)(emb + (size_t)row * DIM + lane * 4);
    float ss = x.x * x.x;
    ss = fmaf(x.y, x.y, ss); ss = fmaf(x.z, x.z, ss); ss = fmaf(x.w, x.w, ss);
#pragma unroll
    for (int off = 1; off <= 32; off <<= 1) ss += __shfl_xor(ss, off);
    float nrm = fmaxf(sqrtf(ss), 1e-12f);
    float4 y; y.x = x.x / nrm; y.y = x.y / nrm; y.z = x.z / nrm; y.w = x.w / nrm;
    *(float4*)(embn + (size_t)row * DIM + lane * 4) = y;
    bf16x4 h; h[0] = (__bf16)y.x; h[1] = (__bf16)y.y; h[2] = (__bf16)y.z; h[3] = (__bf16)y.w;
    *(bf16x4*)(embh + (size_t)row * DIM + lane * 4) = h;
    if (lane == 0) cnt[row] = 0;
}

// ---- Kernel B: MFMA bf16 sim, double-buffered counted-vmcnt pipeline ------
// LDS granule layout per tile (32 k): granule g = kblk*128 + row (16B each);
// round-3-verified: 0 bank conflicts on fragment reads.
__global__ __launch_bounds__(256, 5)
void sim_filter_k(const __bf16* __restrict__ embh, int* __restrict__ cnt,
                  int* __restrict__ cidx) {
    __shared__ __align__(16) __bf16 As[2][BM * 32];   // 2 x 8 KB
    __shared__ __align__(16) __bf16 Bs[2][BM * 32];   // 2 x 8 KB

    int t = blockIdx.x;                       // triangular decode: bj <= bi
    int bi = (int)((sqrtf(8.0f * (float)t + 1.0f) - 1.0f) * 0.5f);
    while ((bi + 1) * (bi + 2) / 2 <= t) ++bi;
    while (bi * (bi + 1) / 2 > t) --bi;
    int bj = t - bi * (bi + 1) / 2;
    const int i0 = bi * BM, j0 = bj * BM;

    const int tid = threadIdx.x;
    const int lane = tid & 63;
    const int ws = tid >> 6;                  // wave id 0..3
    const int wm = ws >> 1, wn = ws & 1;      // 2x2 wave grid, 64x64 each
    const int lr = lane & 15, kb = lane >> 4;

    const int gm = tid & 127;                 // staging row
    const int gk1 = tid >> 7, gk2 = gk1 + 2;  // staging k-chunks

    f32x4 acc[4][4];
#pragma unroll
    for (int m = 0; m < 4; ++m)
#pragma unroll
        for (int n = 0; n < 4; ++n) { f32x4 z = {0.f, 0.f, 0.f, 0.f}; acc[m][n] = z; }

    const __bf16* rowA = embh + (size_t)(i0 + gm) * DIM;
    const __bf16* rowB = embh + (size_t)(j0 + gm) * DIM;

    // stage tile (4 wave-level gload_lds instructions per wave)
    auto stage = [&](int kt, int buf) {
        gload_lds16(rowA + kt + gk1 * 8, &As[buf][(size_t)tid * 8]);
        gload_lds16(rowA + kt + gk2 * 8, &As[buf][((size_t)tid + 256) * 8]);
        gload_lds16(rowB + kt + gk1 * 8, &Bs[buf][(size_t)tid * 8]);
        gload_lds16(rowB + kt + gk2 * 8, &Bs[buf][((size_t)tid + 256) * 8]);
    };

    stage(0, 0);                              // prologue: tile 0 in flight
#pragma unroll
    for (int tk = 0; tk < 8; ++tk) {
        const int cur = tk & 1;
        if (tk < 7) {
            stage((tk + 1) * 32, cur ^ 1);    // issue next tile into other buffer
            asm volatile("s_waitcnt vmcnt(4)" ::: "memory");   // tile tk landed
        } else {
            asm volatile("s_waitcnt vmcnt(0)" ::: "memory");
        }
        __builtin_amdgcn_s_barrier();         // all waves see tile tk in LDS

        bf16x8 a[4], b[4];
#pragma unroll
        for (int f = 0; f < 4; ++f) {
            a[f] = *(const bf16x8*)&As[cur][(size_t)(kb * 128 + wm * 64 + f * 16 + lr) * 8];
            b[f] = *(const bf16x8*)&Bs[cur][(size_t)(kb * 128 + wn * 64 + f * 16 + lr) * 8];
        }
#pragma unroll
        for (int m = 0; m < 4; ++m)
#pragma unroll
            for (int n = 0; n < 4; ++n)
                acc[m][n] = __builtin_amdgcn_mfma_f32_16x16x32_bf16(a[m], b[n], acc[m][n], 0, 0, 0);

        if (tk < 7) __builtin_amdgcn_s_barrier();  // readers done before overwrite
    }

    // epilogue: rare filtered atomic append (indices only; fp32 rescue later)
#pragma unroll
    for (int m = 0; m < 4; ++m) {
        int i = i0 + wm * 64 + m * 16 + kb * 4;
#pragma unroll
        for (int n = 0; n < 4; ++n) {
            int j = j0 + wn * 64 + n * 16 + lr;
#pragma unroll
            for (int r = 0; r < 4; ++r) {
                float v = acc[m][n][r];
                int ii = i + r;
                if (v > FILT && j <= ii - 2) {
                    int c = atomicAdd(&cnt[ii], 1);
                    if (c < CAP) cidx[(size_t)ii * CAP + c] = j;
                }
            }
        }
    }
}

// ---- Kernel C: fp32-exact rescue + (optionally fused) output writes -------
template<bool FUSE>
__global__ void rescue_k(const float* __restrict__ embn, const int* __restrict__ cnt,
                         const int* __restrict__ cidx, const float* __restrict__ table,
                         float* __restrict__ out) {
    int lane = threadIdx.x & 63;
    int i = blockIdx.x * 4 + (threadIdx.x >> 6);
    int nc = cnt[i]; if (nc > CAP) nc = CAP;

    float fv[KS]; int fx[KS];
#pragma unroll
    for (int k = 0; k < KS; ++k) { fv[k] = -1e30f; fx[k] = -1; }

    if (nc > 0) {
        const float4 a = *(const float4*)(embn + (size_t)i * DIM + lane * 4);
        for (int c = 0; c < nc; ++c) {
            int j = cidx[(size_t)i * CAP + c];
            const float4 b = *(const float4*)(embn + (size_t)j * DIM + lane * 4);
            float p = a.x * b.x;
            p = fmaf(a.y, b.y, p); p = fmaf(a.z, b.z, p); p = fmaf(a.w, b.w, p);
#pragma unroll
            for (int off = 1; off <= 32; off <<= 1) p += __shfl_xor(p, off);
            if (p > THRESH) ins5(p, j, fv, fx);   // identical on all lanes
        }
    }
    int vcnt = 0;
#pragma unroll
    for (int k = 0; k < KS; ++k) vcnt += (fv[k] > THRESH) ? 1 : 0;

    float tsem = FUSE ? table[64 + lane] : 0.0f;
#pragma unroll
    for (int k = 0; k < KS; ++k) {
        int e = N_TEMPORAL + i * KS + k;
        bool val = (k < vcnt);
        if (lane == 0) {
            out[e]             = val ? (float)fx[k] : -1.0f;
            out[N_EDGES + e]   = val ? (float)i     : -1.0f;
            out[VALID_OFF + e] = val ? 1.0f : 0.0f;
        }
        if (FUSE) out[ATTR_OFF + (size_t)e * 64 + lane] = val ? tsem : 0.0f;
    }
    if (FUSE) {
        if (i < N_MSG - 1) {
            float ttem = table[lane];
            int e0 = 2 * i;
            out[ATTR_OFF + (size_t)e0 * 64 + lane]       = ttem;
            out[ATTR_OFF + (size_t)(e0 + 1) * 64 + lane] = ttem;
            if (lane == 0) {
                out[e0]                 = (float)i;
                out[N_EDGES + e0]       = (float)(i + 1);
                out[VALID_OFF + e0]     = 1.0f;
                out[e0 + 1]             = (float)(i + 1);
                out[N_EDGES + e0 + 1]   = (float)i;
                out[VALID_OFF + e0 + 1] = 1.0f;
            }
        }
    }
}

// ---- Kernel D (fallback only, when scratch carved from attr region) -------
__global__ void attr_out_k(const float* __restrict__ table, float* __restrict__ out) {
    int idx = blockIdx.x * 256 + threadIdx.x;
    int e = idx >> 4, sub = idx & 15;
    if (e >= N_EDGES) return;
    float4 a4;
    if (e < N_TEMPORAL) {
        a4 = *(const float4*)(table + sub * 4);
        if (sub == 0) {
            int i = e >> 1;
            out[e]             = (e & 1) ? (float)(i + 1) : (float)i;
            out[N_EDGES + e]   = (e & 1) ? (float)i       : (float)(i + 1);
            out[VALID_OFF + e] = 1.0f;
        }
    } else {
        float vld = out[VALID_OFF + e];
        a4 = *(const float4*)(table + 64 + sub * 4);
        a4.x *= vld; a4.y *= vld; a4.z *= vld; a4.w *= vld;
    }
    *(float4*)(out + ATTR_OFF + (size_t)e * 64 + sub * 4) = a4;
}

extern "C" void kernel_launch(void* const* d_in, const int* in_sizes, int n_in,
                              void* d_out, int out_size, void* d_ws, size_t ws_size,
                              hipStream_t stream) {
    const float* emb   = (const float*)d_in[0];
    const float* table = (const float*)d_in[1];
    float* out = (float*)d_out;

    size_t embn_f  = (size_t)N_MSG * DIM;              // 2,097,152 floats (8.39 MB)
    size_t embh_f  = (size_t)N_MSG * DIM / 2;          // bf16 array = 4.19 MB
    size_t cidx_f  = (size_t)N_MSG * CAP;              // 1 MB
    size_t cnt_f   = N_MSG;                            // 32 KB
    size_t need_bytes = (embn_f + embh_f + cidx_f + cnt_f) * 4;  // ~13.7 MB

    bool have_ws = (ws_size >= need_bytes);
    float* scratch = have_ws ? (float*)d_ws
                             : out + ATTR_OFF;  // carve attr region; attr written last
    float*  embn = scratch;
    __bf16* embh = (__bf16*)(scratch + embn_f);
    int*    cidx = (int*)(scratch + embn_f + embh_f);
    int*    cnt  = (int*)(scratch + embn_f + embh_f + cidx_f);

    normalize_k<<<N_MSG / 4, 256, 0, stream>>>(emb, embn, embh, cnt);
    sim_filter_k<<<NBLOCKS, 256, 0, stream>>>(embh, cnt, cidx);
    if (have_ws) {
        rescue_k<true><<<N_MSG / 4, 256, 0, stream>>>(embn, cnt, cidx, table, out);
    } else {
        rescue_k<false><<<N_MSG / 4, 256, 0, stream>>>(embn, cnt, cidx, table, out);
        attr_out_k<<<((size_t)N_EDGES * 16 + 255) / 256, 256, 0, stream>>>(table, out);
    }
}

// Round 7
// 71.617 us; speedup vs baseline: 1.2916x; 1.2916x over previous
//
#include <hip/hip_runtime.h>

#define N_MSG 8192
#define DIM 256
#define KS 5
#define THRESH 0.2f
#define QSCALE 192.0f
#define FILT_I 6672                          // 0.181 * 192^2 (~9-sigma quant margin)
#define N_TEMPORAL (2*(N_MSG-1))             // 16382
#define N_EDGES (N_TEMPORAL + N_MSG*KS)      // 57342
#define ATTR_OFF (2*N_EDGES)                 // 114684
#define VALID_OFF (ATTR_OFF + N_EDGES*64)    // 3784572
#define BM 128
#define NTILE (N_MSG / BM)                   // 64
#define NBLOCKS (NTILE*(NTILE+1)/2)          // 2080
#define CAP 32

typedef int   i32x4 __attribute__((ext_vector_type(4)));

__device__ __forceinline__ void gload_lds16(const void* g, void* l) {
    __builtin_amdgcn_global_load_lds(
        (const __attribute__((address_space(1))) void*)g,
        (__attribute__((address_space(3))) void*)l, 16, 0, 0);
}

// Insert (v, j) into descending-sorted top-5 (ties: lower index first).
__device__ __forceinline__ void ins5(float v, int j, float (&vv)[KS], int (&xx)[KS]) {
    float cv = v; int cj = j;
#pragma unroll
    for (int k = 0; k < KS; ++k) {
        bool b = (cv > vv[k]) || (cv == vv[k] && cj < xx[k]);
        float tv = b ? vv[k] : cv; int tj = b ? xx[k] : cj;
        vv[k] = b ? cv : vv[k];    xx[k] = b ? cj : xx[k];
        cv = tv; cj = tj;
    }
}

// ---- Kernel A: L2-normalize rows -> fp32 copy + int8 quantized copy -------
__global__ void normalize_k(const float* __restrict__ emb, float* __restrict__ embn,
                            unsigned int* __restrict__ embq, int* __restrict__ cnt) {
    int lane = threadIdx.x & 63;
    int row = blockIdx.x * 4 + (threadIdx.x >> 6);
    const float4 x = *(const float4*)(emb + (size_t)row * DIM + lane * 4);
    float ss = x.x * x.x;
    ss = fmaf(x.y, x.y, ss); ss = fmaf(x.z, x.z, ss); ss = fmaf(x.w, x.w, ss);
#pragma unroll
    for (int off = 1; off <= 32; off <<= 1) ss += __shfl_xor(ss, off);
    float nrm = fmaxf(sqrtf(ss), 1e-12f);
    float4 y; y.x = x.x / nrm; y.y = x.y / nrm; y.z = x.z / nrm; y.w = x.w / nrm;
    *(float4*)(embn + (size_t)row * DIM + lane * 4) = y;
    int q0 = (int)rintf(fminf(fmaxf(y.x * QSCALE, -127.f), 127.f));
    int q1 = (int)rintf(fminf(fmaxf(y.y * QSCALE, -127.f), 127.f));
    int q2 = (int)rintf(fminf(fmaxf(y.z * QSCALE, -127.f), 127.f));
    int q3 = (int)rintf(fminf(fmaxf(y.w * QSCALE, -127.f), 127.f));
    embq[(size_t)row * 64 + lane] =
        (q0 & 255) | ((q1 & 255) << 8) | ((q2 & 255) << 16) | ((q3 & 255) << 24);
    if (lane == 0) cnt[row] = 0;
}

// ---- Kernel B: i8 MFMA sim filter, round-5-proven dbuf counted-vmcnt ------
// LDS granule layout per 64-k step: granule g = kblk*128 + row (16B = 16 i8);
// fragment reads ds_read_b128, conflict-free (same pattern as verified bf16).
__global__ __launch_bounds__(256, 4)
void sim_filter_k(const signed char* __restrict__ embq, int* __restrict__ cnt,
                  int* __restrict__ cidx) {
    __shared__ __align__(16) signed char Aq[2][BM * 64];   // 2 x 8 KB
    __shared__ __align__(16) signed char Bq[2][BM * 64];   // 2 x 8 KB

    int t = blockIdx.x;                       // triangular decode: bj <= bi
    int bi = (int)((sqrtf(8.0f * (float)t + 1.0f) - 1.0f) * 0.5f);
    while ((bi + 1) * (bi + 2) / 2 <= t) ++bi;
    while (bi * (bi + 1) / 2 > t) --bi;
    int bj = t - bi * (bi + 1) / 2;
    const int i0 = bi * BM, j0 = bj * BM;

    const int tid = threadIdx.x;
    const int lane = tid & 63;
    const int ws = tid >> 6;                  // wave id 0..3
    const int wm = ws >> 1, wn = ws & 1;      // 2x2 wave grid, 64x64 each
    const int lr = lane & 15, kb = lane >> 4;

    const int gm = tid & 127;                 // staging row
    const int gk1 = tid >> 7, gk2 = gk1 + 2;  // staging k-granules (16B each)

    const signed char* rowA = embq + (size_t)(i0 + gm) * DIM;
    const signed char* rowB = embq + (size_t)(j0 + gm) * DIM;

    // stage one 64-k step (4 gload_lds per thread); trailing fence pins the
    // wave-level issue order so counted vmcnt() arithmetic stays valid.
    auto stage = [&](int step, int buf) {
        gload_lds16(rowA + step * 64 + gk1 * 16, &Aq[buf][(size_t)tid * 16]);
        gload_lds16(rowA + step * 64 + gk2 * 16, &Aq[buf][((size_t)tid + 256) * 16]);
        gload_lds16(rowB + step * 64 + gk1 * 16, &Bq[buf][(size_t)tid * 16]);
        gload_lds16(rowB + step * 64 + gk2 * 16, &Bq[buf][((size_t)tid + 256) * 16]);
        asm volatile("" ::: "memory");
    };

    i32x4 acc[4][4];
#pragma unroll
    for (int m = 0; m < 4; ++m)
#pragma unroll
        for (int n = 0; n < 4; ++n) { i32x4 z = {0, 0, 0, 0}; acc[m][n] = z; }

    auto compute = [&](int slot) {
        i32x4 a[4], b[4];
#pragma unroll
        for (int f = 0; f < 4; ++f) {
            a[f] = *(const i32x4*)&Aq[slot][(size_t)(kb * 128 + wm * 64 + f * 16 + lr) * 16];
            b[f] = *(const i32x4*)&Bq[slot][(size_t)(kb * 128 + wn * 64 + f * 16 + lr) * 16];
        }
#pragma unroll
        for (int m = 0; m < 4; ++m)
#pragma unroll
            for (int n = 0; n < 4; ++n)
                acc[m][n] = __builtin_amdgcn_mfma_i32_16x16x64_i8(a[m], b[n], acc[m][n], 0, 0, 0);
    };

    stage(0, 0);                              // prologue: step 0 in flight
#pragma unroll
    for (int tk = 0; tk < 4; ++tk) {
        const int cur = tk & 1;
        if (tk < 3) {
            stage(tk + 1, cur ^ 1);           // issue next step into other buffer
            asm volatile("s_waitcnt vmcnt(4)" ::: "memory");   // step tk landed
        } else {
            asm volatile("s_waitcnt vmcnt(0)" ::: "memory");
        }
        __builtin_amdgcn_s_barrier();         // all waves see step tk in LDS
        __builtin_amdgcn_sched_barrier(0);    // keep LDS reads below the barrier
        compute(cur);
        if (tk < 3) {
            __builtin_amdgcn_sched_barrier(0);
            __builtin_amdgcn_s_barrier();     // readers done before overwrite
        }
    }

    // epilogue: rare filtered atomic append (indices only; fp32 rescue later)
#pragma unroll
    for (int m = 0; m < 4; ++m) {
        int i = i0 + wm * 64 + m * 16 + kb * 4;
#pragma unroll
        for (int n = 0; n < 4; ++n) {
            int j = j0 + wn * 64 + n * 16 + lr;
#pragma unroll
            for (int r = 0; r < 4; ++r) {
                int v = acc[m][n][r];
                int ii = i + r;
                if (v > FILT_I && j <= ii - 2) {
                    int c = atomicAdd(&cnt[ii], 1);
                    if (c < CAP) cidx[(size_t)ii * CAP + c] = j;
                }
            }
        }
    }
}

// ---- Kernel C: fp32-exact rescue + (optionally fused) output writes -------
template<bool FUSE>
__global__ void rescue_k(const float* __restrict__ embn, const int* __restrict__ cnt,
                         const int* __restrict__ cidx, const float* __restrict__ table,
                         float* __restrict__ out) {
    int lane = threadIdx.x & 63;
    int i = blockIdx.x * 4 + (threadIdx.x >> 6);
    int nc = cnt[i]; if (nc > CAP) nc = CAP;

    float fv[KS]; int fx[KS];
#pragma unroll
    for (int k = 0; k < KS; ++k) { fv[k] = -1e30f; fx[k] = -1; }

    if (nc > 0) {
        const float4 a = *(const float4*)(embn + (size_t)i * DIM + lane * 4);
        for (int c = 0; c < nc; ++c) {
            int j = cidx[(size_t)i * CAP + c];
            const float4 b = *(const float4*)(embn + (size_t)j * DIM + lane * 4);
            float p = a.x * b.x;
            p = fmaf(a.y, b.y, p); p = fmaf(a.z, b.z, p); p = fmaf(a.w, b.w, p);
#pragma unroll
            for (int off = 1; off <= 32; off <<= 1) p += __shfl_xor(p, off);
            if (p > THRESH) ins5(p, j, fv, fx);   // identical on all lanes
        }
    }
    int vcnt = 0;
#pragma unroll
    for (int k = 0; k < KS; ++k) vcnt += (fv[k] > THRESH) ? 1 : 0;

    float tsem = FUSE ? table[64 + lane] : 0.0f;
#pragma unroll
    for (int k = 0; k < KS; ++k) {
        int e = N_TEMPORAL + i * KS + k;
        bool val = (k < vcnt);
        if (lane == 0) {
            out[e]             = val ? (float)fx[k] : -1.0f;
            out[N_EDGES + e]   = val ? (float)i     : -1.0f;
            out[VALID_OFF + e] = val ? 1.0f : 0.0f;
        }
        if (FUSE) out[ATTR_OFF + (size_t)e * 64 + lane] = val ? tsem : 0.0f;
    }
    if (FUSE) {
        if (i < N_MSG - 1) {
            float ttem = table[lane];
            int e0 = 2 * i;
            out[ATTR_OFF + (size_t)e0 * 64 + lane]       = ttem;
            out[ATTR_OFF + (size_t)(e0 + 1) * 64 + lane] = ttem;
            if (lane == 0) {
                out[e0]                 = (float)i;
                out[N_EDGES + e0]       = (float)(i + 1);
                out[VALID_OFF + e0]     = 1.0f;
                out[e0 + 1]             = (float)(i + 1);
                out[N_EDGES + e0 + 1]   = (float)i;
                out[VALID_OFF + e0 + 1] = 1.0f;
            }
        }
    }
}

// ---- Kernel D (fallback only, when scratch carved from attr region) -------
__global__ void attr_out_k(const float* __restrict__ table, float* __restrict__ out) {
    int idx = blockIdx.x * 256 + threadIdx.x;
    int e = idx >> 4, sub = idx & 15;
    if (e >= N_EDGES) return;
    float4 a4;
    if (e < N_TEMPORAL) {
        a4 = *(const float4*)(table + sub * 4);
        if (sub == 0) {
            int i = e >> 1;
            out[e]             = (e & 1) ? (float)(i + 1) : (float)i;
            out[N_EDGES + e]   = (e & 1) ? (float)i       : (float)(i + 1);
            out[VALID_OFF + e] = 1.0f;
        }
    } else {
        float vld = out[VALID_OFF + e];
        a4 = *(const float4*)(table + 64 + sub * 4);
        a4.x *= vld; a4.y *= vld; a4.z *= vld; a4.w *= vld;
    }
    *(float4*)(out + ATTR_OFF + (size_t)e * 64 + sub * 4) = a4;
}

extern "C" void kernel_launch(void* const* d_in, const int* in_sizes, int n_in,
                              void* d_out, int out_size, void* d_ws, size_t ws_size,
                              hipStream_t stream) {
    const float* emb   = (const float*)d_in[0];
    const float* table = (const float*)d_in[1];
    float* out = (float*)d_out;

    size_t embn_f  = (size_t)N_MSG * DIM;              // 2,097,152 floats (8.39 MB)
    size_t embq_f  = (size_t)N_MSG * DIM / 4;          // i8 array = 2.10 MB
    size_t cidx_f  = (size_t)N_MSG * CAP;              // 1 MB
    size_t cnt_f   = N_MSG;                            // 32 KB
    size_t need_bytes = (embn_f + embq_f + cidx_f + cnt_f) * 4;  // ~11.5 MB

    bool have_ws = (ws_size >= need_bytes);
    float* scratch = have_ws ? (float*)d_ws
                             : out + ATTR_OFF;  // carve attr region; attr written last
    float*        embn = scratch;
    unsigned int* embq = (unsigned int*)(scratch + embn_f);
    int*          cidx = (int*)(scratch + embn_f + embq_f);
    int*          cnt  = (int*)(scratch + embn_f + embq_f + cidx_f);

    normalize_k<<<N_MSG / 4, 256, 0, stream>>>(emb, embn, embq, cnt);
    sim_filter_k<<<NBLOCKS, 256, 0, stream>>>((const signed char*)embq, cnt, cidx);
    if (have_ws) {
        rescue_k<true><<<N_MSG / 4, 256, 0, stream>>>(embn, cnt, cidx, table, out);
    } else {
        rescue_k<false><<<N_MSG / 4, 256, 0, stream>>>(embn, cnt, cidx, table, out);
        attr_out_k<<<((size_t)N_EDGES * 16 + 255) / 256, 256, 0, stream>>>(table, out);
    }
}

// Round 8
// 62.832 us; speedup vs baseline: 1.4722x; 1.1398x over previous
//
#include <hip/hip_runtime.h>

#define N_MSG 8192
#define DIM 256
#define KS 5
#define THRESH 0.2f
#define QSCALE 192.0f
#define FILT_I 6672                          // 0.181 * 192^2 (~9-sigma quant margin)
#define N_TEMPORAL (2*(N_MSG-1))             // 16382
#define N_EDGES (N_TEMPORAL + N_MSG*KS)      // 57342
#define ATTR_OFF (2*N_EDGES)                 // 114684
#define VALID_OFF (ATTR_OFF + N_EDGES*64)    // 3784572
#define BM 128
#define NTILE (N_MSG / BM)                   // 64
#define NBLOCKS (NTILE*(NTILE+1)/2)          // 2080
#define CAP 32

typedef int i32x4 __attribute__((ext_vector_type(4)));

// Insert (v, j) into descending-sorted top-5 (ties: lower index first).
__device__ __forceinline__ void ins5(float v, int j, float (&vv)[KS], int (&xx)[KS]) {
    float cv = v; int cj = j;
#pragma unroll
    for (int k = 0; k < KS; ++k) {
        bool b = (cv > vv[k]) || (cv == vv[k] && cj < xx[k]);
        float tv = b ? vv[k] : cv; int tj = b ? xx[k] : cj;
        vv[k] = b ? cv : vv[k];    xx[k] = b ? cj : xx[k];
        cv = tv; cj = tj;
    }
}

// ---- Kernel A: L2-normalize rows -> fp32 copy + TRANSPOSED int8 quant -----
// embqT chunk layout (16 B = 16 i8): chunk_id = c16 * N_MSG + row, where
// c16 = k/16 (0..15). This is exactly the mfma_i32_16x16x64_i8 fragment
// order verified by round 7: lane-group kb reads k in [kb*16, kb*16+16).
__global__ void normalize_k(const float* __restrict__ emb, float* __restrict__ embn,
                            unsigned int* __restrict__ embqT, int* __restrict__ cnt) {
    int lane = threadIdx.x & 63;
    int row = blockIdx.x * 4 + (threadIdx.x >> 6);
    const float4 x = *(const float4*)(emb + (size_t)row * DIM + lane * 4);
    float ss = x.x * x.x;
    ss = fmaf(x.y, x.y, ss); ss = fmaf(x.z, x.z, ss); ss = fmaf(x.w, x.w, ss);
#pragma unroll
    for (int off = 1; off <= 32; off <<= 1) ss += __shfl_xor(ss, off);
    float nrm = fmaxf(sqrtf(ss), 1e-12f);
    float4 y; y.x = x.x / nrm; y.y = x.y / nrm; y.z = x.z / nrm; y.w = x.w / nrm;
    *(float4*)(embn + (size_t)row * DIM + lane * 4) = y;
    int q0 = (int)rintf(fminf(fmaxf(y.x * QSCALE, -127.f), 127.f));
    int q1 = (int)rintf(fminf(fmaxf(y.y * QSCALE, -127.f), 127.f));
    int q2 = (int)rintf(fminf(fmaxf(y.z * QSCALE, -127.f), 127.f));
    int q3 = (int)rintf(fminf(fmaxf(y.w * QSCALE, -127.f), 127.f));
    unsigned int packed =
        (q0 & 255) | ((q1 & 255) << 8) | ((q2 & 255) << 16) | ((q3 & 255) << 24);
    // elements lane*4..lane*4+3 live in k-chunk c16 = lane>>2, word lane&3
    embqT[(((size_t)(lane >> 2) * N_MSG + row) << 2) | (lane & 3)] = packed;
    if (lane == 0) cnt[row] = 0;
}

// ---- Kernel B: i8 MFMA sim filter — NO LDS, direct coalesced frag loads ---
// Each block: 4 waves in 2x2 grid over a 128x128 tile; per wave 64x64 out.
// Fragment loads hit L2 (2.1 MB table is XCD-L2-resident); no barriers.
__global__ __launch_bounds__(256, 4)
void sim_filter_k(const i32x4* __restrict__ T, int* __restrict__ cnt,
                  int* __restrict__ cidx) {
    int t = blockIdx.x;                       // triangular decode: bj <= bi
    int bi = (int)((sqrtf(8.0f * (float)t + 1.0f) - 1.0f) * 0.5f);
    while ((bi + 1) * (bi + 2) / 2 <= t) ++bi;
    while (bi * (bi + 1) / 2 > t) --bi;
    int bj = t - bi * (bi + 1) / 2;
    const int i0 = bi * BM, j0 = bj * BM;

    const int tid = threadIdx.x;
    const int lane = tid & 63;
    const int ws = tid >> 6;                  // wave id 0..3
    const int wm = ws >> 1, wn = ws & 1;      // 2x2 wave grid, 64x64 each
    const int lr = lane & 15, kb = lane >> 4;

    i32x4 acc[4][4];
#pragma unroll
    for (int m = 0; m < 4; ++m)
#pragma unroll
        for (int n = 0; n < 4; ++n) { i32x4 z = {0, 0, 0, 0}; acc[m][n] = z; }

#pragma unroll
    for (int kc = 0; kc < 4; ++kc) {
        const i32x4* Tc = T + (size_t)(kc * 4 + kb) * N_MSG;
        i32x4 a[4], b[4];
#pragma unroll
        for (int f = 0; f < 4; ++f) {
            a[f] = Tc[i0 + wm * 64 + f * 16 + lr];
            b[f] = Tc[j0 + wn * 64 + f * 16 + lr];
        }
#pragma unroll
        for (int m = 0; m < 4; ++m)
#pragma unroll
            for (int n = 0; n < 4; ++n)
                acc[m][n] = __builtin_amdgcn_mfma_i32_16x16x64_i8(a[m], b[n], acc[m][n], 0, 0, 0);
    }

    // epilogue: rare filtered atomic append (indices only; fp32 rescue later)
#pragma unroll
    for (int m = 0; m < 4; ++m) {
        int i = i0 + wm * 64 + m * 16 + kb * 4;
#pragma unroll
        for (int n = 0; n < 4; ++n) {
            int j = j0 + wn * 64 + n * 16 + lr;
#pragma unroll
            for (int r = 0; r < 4; ++r) {
                int v = acc[m][n][r];
                int ii = i + r;
                if (v > FILT_I && j <= ii - 2) {
                    int c = atomicAdd(&cnt[ii], 1);
                    if (c < CAP) cidx[(size_t)ii * CAP + c] = j;
                }
            }
        }
    }
}

// ---- Kernel C: fp32-exact rescue + (optionally fused) output writes -------
template<bool FUSE>
__global__ void rescue_k(const float* __restrict__ embn, const int* __restrict__ cnt,
                         const int* __restrict__ cidx, const float* __restrict__ table,
                         float* __restrict__ out) {
    int lane = threadIdx.x & 63;
    int i = blockIdx.x * 4 + (threadIdx.x >> 6);
    int nc = cnt[i]; if (nc > CAP) nc = CAP;

    float fv[KS]; int fx[KS];
#pragma unroll
    for (int k = 0; k < KS; ++k) { fv[k] = -1e30f; fx[k] = -1; }

    if (nc > 0) {
        const float4 a = *(const float4*)(embn + (size_t)i * DIM + lane * 4);
        for (int c = 0; c < nc; ++c) {
            int j = cidx[(size_t)i * CAP + c];
            const float4 b = *(const float4*)(embn + (size_t)j * DIM + lane * 4);
            float p = a.x * b.x;
            p = fmaf(a.y, b.y, p); p = fmaf(a.z, b.z, p); p = fmaf(a.w, b.w, p);
#pragma unroll
            for (int off = 1; off <= 32; off <<= 1) p += __shfl_xor(p, off);
            if (p > THRESH) ins5(p, j, fv, fx);   // identical on all lanes
        }
    }
    int vcnt = 0;
#pragma unroll
    for (int k = 0; k < KS; ++k) vcnt += (fv[k] > THRESH) ? 1 : 0;

    float tsem = FUSE ? table[64 + lane] : 0.0f;
#pragma unroll
    for (int k = 0; k < KS; ++k) {
        int e = N_TEMPORAL + i * KS + k;
        bool val = (k < vcnt);
        if (lane == 0) {
            out[e]             = val ? (float)fx[k] : -1.0f;
            out[N_EDGES + e]   = val ? (float)i     : -1.0f;
            out[VALID_OFF + e] = val ? 1.0f : 0.0f;
        }
        if (FUSE) out[ATTR_OFF + (size_t)e * 64 + lane] = val ? tsem : 0.0f;
    }
    if (FUSE) {
        if (i < N_MSG - 1) {
            float ttem = table[lane];
            int e0 = 2 * i;
            out[ATTR_OFF + (size_t)e0 * 64 + lane]       = ttem;
            out[ATTR_OFF + (size_t)(e0 + 1) * 64 + lane] = ttem;
            if (lane == 0) {
                out[e0]                 = (float)i;
                out[N_EDGES + e0]       = (float)(i + 1);
                out[VALID_OFF + e0]     = 1.0f;
                out[e0 + 1]             = (float)(i + 1);
                out[N_EDGES + e0 + 1]   = (float)i;
                out[VALID_OFF + e0 + 1] = 1.0f;
            }
        }
    }
}

// ---- Kernel D (fallback only, when scratch carved from attr region) -------
__global__ void attr_out_k(const float* __restrict__ table, float* __restrict__ out) {
    int idx = blockIdx.x * 256 + threadIdx.x;
    int e = idx >> 4, sub = idx & 15;
    if (e >= N_EDGES) return;
    float4 a4;
    if (e < N_TEMPORAL) {
        a4 = *(const float4*)(table + sub * 4);
        if (sub == 0) {
            int i = e >> 1;
            out[e]             = (e & 1) ? (float)(i + 1) : (float)i;
            out[N_EDGES + e]   = (e & 1) ? (float)i       : (float)(i + 1);
            out[VALID_OFF + e] = 1.0f;
        }
    } else {
        float vld = out[VALID_OFF + e];
        a4 = *(const float4*)(table + 64 + sub * 4);
        a4.x *= vld; a4.y *= vld; a4.z *= vld; a4.w *= vld;
    }
    *(float4*)(out + ATTR_OFF + (size_t)e * 64 + sub * 4) = a4;
}

extern "C" void kernel_launch(void* const* d_in, const int* in_sizes, int n_in,
                              void* d_out, int out_size, void* d_ws, size_t ws_size,
                              hipStream_t stream) {
    const float* emb   = (const float*)d_in[0];
    const float* table = (const float*)d_in[1];
    float* out = (float*)d_out;

    size_t embn_f  = (size_t)N_MSG * DIM;              // 2,097,152 floats (8.39 MB)
    size_t embq_f  = (size_t)N_MSG * DIM / 4;          // i8 table = 2.10 MB
    size_t cidx_f  = (size_t)N_MSG * CAP;              // 1 MB
    size_t cnt_f   = N_MSG;                            // 32 KB
    size_t need_bytes = (embn_f + embq_f + cidx_f + cnt_f) * 4;  // ~11.5 MB

    bool have_ws = (ws_size >= need_bytes);
    float* scratch = have_ws ? (float*)d_ws
                             : out + ATTR_OFF;  // carve attr region; attr written last
    float*        embn  = scratch;
    unsigned int* embqT = (unsigned int*)(scratch + embn_f);
    int*          cidx  = (int*)(scratch + embn_f + embq_f);
    int*          cnt   = (int*)(scratch + embn_f + embq_f + cidx_f);

    normalize_k<<<N_MSG / 4, 256, 0, stream>>>(emb, embn, embqT, cnt);
    sim_filter_k<<<NBLOCKS, 256, 0, stream>>>((const i32x4*)embqT, cnt, cidx);
    if (have_ws) {
        rescue_k<true><<<N_MSG / 4, 256, 0, stream>>>(embn, cnt, cidx, table, out);
    } else {
        rescue_k<false><<<N_MSG / 4, 256, 0, stream>>>(embn, cnt, cidx, table, out);
        attr_out_k<<<((size_t)N_EDGES * 16 + 255) / 256, 256, 0, stream>>>(table, out);
    }
}